// Round 1
// baseline (2255.945 us; speedup 1.0000x reference)
//
#include <hip/hip_runtime.h>

// Sinkhorn EMD: B=8, N=2048, eps=0.005, 50 iters.
// Log2-domain formulation: K = eps*ln2
//   y'_j = a_j + p_i . G_j,  G_j = 2*g_j/K, a_j = (pot_j - |g_j|^2)/K
//   f_i  = eps*log_marg + |p_i|^2 - K * LSE2_j(y'_j)
// One v_exp_f32 per element on the common (no-new-max) path.

#define BB 8
#define NN 2048
#define NITERS 50
#define RPW 4                       // rows per wave (LDS amortization)
#define WAVES 4
#define ROWS_PER_BLOCK (RPW * WAVES) // 16

constexpr float EPSV = 0.005f;
constexpr float LN2V = 0.69314718055994531f;
constexpr float KS   = EPSV * LN2V;        // eps*ln2
constexpr float INVK = 1.0f / KS;
constexpr float C1V  = -EPSV * 7.6246189861593985f; // eps*log(1/N) = -eps*ln(2048)

__device__ __forceinline__ float fexp2(float x) { return __builtin_amdgcn_exp2f(x); }
__device__ __forceinline__ float flog2(float x) { return __builtin_amdgcn_logf(x); }

// One Sinkhorn half-iteration. rows=points whose potential is updated,
// cols=points summed over (their current potential is pot_in).
__global__ __launch_bounds__(256) void sink_pass(
    const float* __restrict__ rpts, const float* __restrict__ cpts,
    const float* __restrict__ pot_in, float* __restrict__ pot_out)
{
    __shared__ float4 sj[NN]; // {Gx, Gy, Gz, a}

    const int b = blockIdx.y;
    const float* cp  = cpts   + (size_t)b * NN * 3;
    const float* pin = pot_in + (size_t)b * NN;
    for (int t = threadIdx.x; t < NN; t += 256) {
        float gx = cp[3*t], gy = cp[3*t+1], gz = cp[3*t+2];
        float n2 = gx*gx + gy*gy + gz*gz;
        sj[t] = make_float4(gx * (2.0f*INVK), gy * (2.0f*INVK), gz * (2.0f*INVK),
                            (pin[t] - n2) * INVK);
    }
    __syncthreads();

    const int wave = threadIdx.x >> 6;
    const int lane = threadIdx.x & 63;
    const int row0 = blockIdx.x * ROWS_PER_BLOCK + wave * RPW;
    const float* rp = rpts + (size_t)b * NN * 3;

    float px[RPW], py[RPW], pz[RPW], pn[RPW], m[RPW], s[RPW];
#pragma unroll
    for (int r = 0; r < RPW; ++r) {
        int i = row0 + r;
        px[r] = rp[3*i]; py[r] = rp[3*i+1]; pz[r] = rp[3*i+2];
        pn[r] = px[r]*px[r] + py[r]*py[r] + pz[r]*pz[r];
        m[r] = -1e30f; s[r] = 0.0f;
    }

    for (int c = 0; c < NN/64; ++c) {
        float4 d = sj[c*64 + lane];
        float x[RPW];
#pragma unroll
        for (int r = 0; r < RPW; ++r)
            x[r] = fmaf(px[r], d.x, fmaf(py[r], d.y, fmaf(pz[r], d.z, d.w)));
        bool up = false;
#pragma unroll
        for (int r = 0; r < RPW; ++r) up = up || (x[r] > m[r]);
        if (__any((int)up)) {
            // wave-uniform rescale path (rare after warm-up)
#pragma unroll
            for (int r = 0; r < RPW; ++r) {
                float mn = fmaxf(m[r], x[r]);
                s[r] = fmaf(s[r], fexp2(m[r] - mn), fexp2(x[r] - mn));
                m[r] = mn;
            }
        } else {
            // common path: 1 exp per element
#pragma unroll
            for (int r = 0; r < RPW; ++r) s[r] += fexp2(x[r] - m[r]);
        }
    }

    // combine 64 lanes' (m, s) pairs: butterfly LSE-merge
#pragma unroll
    for (int r = 0; r < RPW; ++r) {
        float mm = m[r], ss = s[r];
        for (int off = 1; off < 64; off <<= 1) {
            float mo = __shfl_xor(mm, off, 64);
            float so = __shfl_xor(ss, off, 64);
            float mn = fmaxf(mm, mo);
            ss = fmaf(ss, fexp2(mm - mn), so * fexp2(mo - mn));
            mm = mn;
        }
        if (lane == 0)
            pot_out[(size_t)b*NN + row0 + r] = C1V + pn[r] - KS * (mm + flog2(ss));
    }
}

// Final: out = sum_{b,i,j} P_ij * C_ij / B,  P = 2^{bb_i + a_j + dot},
// C = pn_i + gn_j - K*dot,  dot = p_i . G_j.
__global__ __launch_bounds__(256) void dis_pass(
    const float* __restrict__ preds, const float* __restrict__ gts,
    const float* __restrict__ f, const float* __restrict__ g,
    float* __restrict__ out)
{
    __shared__ float4 sj[NN];
    __shared__ float  sgn[NN];

    const int b = blockIdx.y;
    const float* cp = gts + (size_t)b * NN * 3;
    const float* gg = g   + (size_t)b * NN;
    for (int t = threadIdx.x; t < NN; t += 256) {
        float gx = cp[3*t], gy = cp[3*t+1], gz = cp[3*t+2];
        float n2 = gx*gx + gy*gy + gz*gz;
        sj[t] = make_float4(gx * (2.0f*INVK), gy * (2.0f*INVK), gz * (2.0f*INVK),
                            (gg[t] - n2) * INVK);
        sgn[t] = n2;
    }
    __syncthreads();

    const int wave = threadIdx.x >> 6;
    const int lane = threadIdx.x & 63;
    const int row0 = blockIdx.x * ROWS_PER_BLOCK + wave * RPW;
    const float* rp = preds + (size_t)b * NN * 3;
    const float* ff = f     + (size_t)b * NN;

    float px[RPW], py[RPW], pz[RPW], pn[RPW], bb[RPW], acc[RPW];
#pragma unroll
    for (int r = 0; r < RPW; ++r) {
        int i = row0 + r;
        px[r] = rp[3*i]; py[r] = rp[3*i+1]; pz[r] = rp[3*i+2];
        pn[r] = px[r]*px[r] + py[r]*py[r] + pz[r]*pz[r];
        bb[r] = (ff[i] - pn[r]) * INVK;
        acc[r] = 0.0f;
    }

    for (int c = 0; c < NN/64; ++c) {
        float4 d = sj[c*64 + lane];
        float gn = sgn[c*64 + lane];
#pragma unroll
        for (int r = 0; r < RPW; ++r) {
            float dot = fmaf(px[r], d.x, fmaf(py[r], d.y, pz[r]*d.z));
            float y   = bb[r] + d.w + dot;
            float e   = fexp2(y);
            float Cc  = fmaf(-KS, dot, pn[r] + gn);
            acc[r] = fmaf(e, Cc, acc[r]);
        }
    }

    float tot = acc[0] + acc[1] + acc[2] + acc[3];
    for (int off = 1; off < 64; off <<= 1)
        tot += __shfl_xor(tot, off, 64);
    if (lane == 0)
        atomicAdd(out, tot * (1.0f / BB));
}

extern "C" void kernel_launch(void* const* d_in, const int* in_sizes, int n_in,
                              void* d_out, int out_size, void* d_ws, size_t ws_size,
                              hipStream_t stream) {
    const float* preds = (const float*)d_in[0];
    const float* gts   = (const float*)d_in[1];
    float* f = (float*)d_ws;            // [B*N]
    float* g = f + BB * NN;             // [B*N]
    float* out = (float*)d_out;

    // ws/out are re-poisoned before every call: zero potentials + output.
    hipMemsetAsync(d_ws, 0, 2 * BB * NN * sizeof(float), stream);
    hipMemsetAsync(d_out, 0, sizeof(float), stream);

    dim3 grid(NN / ROWS_PER_BLOCK, BB); // (128, 8)
    for (int it = 0; it < NITERS; ++it) {
        sink_pass<<<grid, 256, 0, stream>>>(preds, gts, g, f); // f-update
        sink_pass<<<grid, 256, 0, stream>>>(gts, preds, f, g); // g-update
    }
    dis_pass<<<grid, 256, 0, stream>>>(preds, gts, f, g, out);
}